// Round 8
// baseline (62.992 us; speedup 1.0000x reference)
//
#include <hip/hip_runtime.h>

#define DIMS 64
#define OUT_Q 8388608   // 32*64*64*64
#define MAIN_WGS 1024   // 128 x-rows per WG

typedef float f32x4 __attribute__((ext_vector_type(4)));
typedef float f4    __attribute__((ext_vector_type(4)));
typedef short short8 __attribute__((ext_vector_type(8)));

union U8 { unsigned int u[4]; short8 s; };

// ws: float[0..1024) per-WG partial loss sums. Nothing else.

#define CVT8(Q, A, B)                                                          \
    asm("v_cvt_pk_bf16_f32 %0, %1, %2" : "=v"(Q.u[0]) : "v"(A[0]), "v"(A[1])); \
    asm("v_cvt_pk_bf16_f32 %0, %1, %2" : "=v"(Q.u[1]) : "v"(A[2]), "v"(A[3])); \
    asm("v_cvt_pk_bf16_f32 %0, %1, %2" : "=v"(Q.u[2]) : "v"(B[0]), "v"(B[1])); \
    asm("v_cvt_pk_bf16_f32 %0, %1, %2" : "=v"(Q.u[3]) : "v"(B[2]), "v"(B[3]));

__global__ __launch_bounds__(512, 4) void vq_main(const float* __restrict__ x,
                                                  const float* __restrict__ cb,
                                                  float* __restrict__ out,
                                                  float* __restrict__ ws) {
    __shared__ float lds_best[8 * 128];   // [wave][row]
    __shared__ float lds_xn[128];
    __shared__ int   lds_idx[128];
    __shared__ float lds_part[2];

    const int tid  = threadIdx.x;
    const int lane = tid & 63;
    const int wid  = tid >> 6;            // 0..7: this wave's K-slice (4 k-tiles)
    const int r15  = lane & 15;
    const int g    = lane >> 4;
    const long wgrow = (long)blockIdx.x * 128;   // first x-row of this WG

    // ---- Phase 0: wave's 64 codebook entries -> registers (B-frag layout),
    //      norms computed from the same fp32 values (no prep kernel).
    short8 B00, B01, B10, B11, B20, B21, B30, B31;
    float ic0, ic1, ic2, ic3;
#define LOADB(KK, B0, B1, IC) {                                                \
        const float* crow_ = cb + (((wid << 2) + KK) * 16 + r15) * DIMS + (g << 3); \
        f4 a_ = *(const f4*)crow_;                                             \
        f4 b_ = *(const f4*)(crow_ + 4);                                       \
        f4 c_ = *(const f4*)(crow_ + 32);                                      \
        f4 d_ = *(const f4*)(crow_ + 36);                                      \
        U8 q_; CVT8(q_, a_, b_) B0 = q_.s; CVT8(q_, c_, d_) B1 = q_.s;         \
        float nn_ = a_[0]*a_[0]+a_[1]*a_[1]+a_[2]*a_[2]+a_[3]*a_[3]            \
                  + b_[0]*b_[0]+b_[1]*b_[1]+b_[2]*b_[2]+b_[3]*b_[3]            \
                  + c_[0]*c_[0]+c_[1]*c_[1]+c_[2]*c_[2]+c_[3]*c_[3]            \
                  + d_[0]*d_[0]+d_[1]*d_[1]+d_[2]*d_[2]+d_[3]*d_[3];           \
        nn_ += __shfl_xor(nn_, 16, 64);  nn_ += __shfl_xor(nn_, 32, 64);       \
        IC = -0.5f * nn_; }
    LOADB(0, B00, B01, ic0)
    LOADB(1, B10, B11, ic1)
    LOADB(2, B20, B21, ic2)
    LOADB(3, B30, B31, ic3)
#undef LOADB

    // ---- Phase 1: stream 8 row-tiles; mantissa-packed argmax (low 9 bits = k)
    float bv00=-3.4e38f, bv01=-3.4e38f, bv02=-3.4e38f, bv03=-3.4e38f;
    float bv10=-3.4e38f, bv11=-3.4e38f, bv12=-3.4e38f, bv13=-3.4e38f;
    float bv20=-3.4e38f, bv21=-3.4e38f, bv22=-3.4e38f, bv23=-3.4e38f;
    float bv30=-3.4e38f, bv31=-3.4e38f, bv32=-3.4e38f, bv33=-3.4e38f;
    float bv40=-3.4e38f, bv41=-3.4e38f, bv42=-3.4e38f, bv43=-3.4e38f;
    float bv50=-3.4e38f, bv51=-3.4e38f, bv52=-3.4e38f, bv53=-3.4e38f;
    float bv60=-3.4e38f, bv61=-3.4e38f, bv62=-3.4e38f, bv63=-3.4e38f;
    float bv70=-3.4e38f, bv71=-3.4e38f, bv72=-3.4e38f, bv73=-3.4e38f;
    float xn0, xn1, xn2, xn3, xn4, xn5, xn6, xn7;

#define KSTEP(KK, B0, B1, IC, BV0, BV1, BV2, BV3) {                            \
        f32x4 init_ = {IC, IC, IC, IC};                                        \
        f32x4 acc_ = __builtin_amdgcn_mfma_f32_16x16x32_bf16(A0_, B0, init_, 0, 0, 0); \
        acc_       = __builtin_amdgcn_mfma_f32_16x16x32_bf16(A1_, B1, acc_, 0, 0, 0);  \
        const unsigned int kr_ = (unsigned int)((((wid << 2) + KK) << 4) + r15); \
        BV0 = fmaxf(BV0, __uint_as_float((__float_as_uint(acc_[0]) & 0xFFFFFE00u) | kr_)); \
        BV1 = fmaxf(BV1, __uint_as_float((__float_as_uint(acc_[1]) & 0xFFFFFE00u) | kr_)); \
        BV2 = fmaxf(BV2, __uint_as_float((__float_as_uint(acc_[2]) & 0xFFFFFE00u) | kr_)); \
        BV3 = fmaxf(BV3, __uint_as_float((__float_as_uint(acc_[3]) & 0xFFFFFE00u) | kr_)); }

#define TILE(T, BV0, BV1, BV2, BV3, XN) {                                      \
        const float* xa_ = x + (wgrow + T * 16 + r15) * DIMS + (g << 3);       \
        f4 a_ = *(const f4*)xa_;                                               \
        f4 b_ = *(const f4*)(xa_ + 4);                                         \
        f4 c_ = *(const f4*)(xa_ + 32);                                        \
        f4 d_ = *(const f4*)(xa_ + 36);                                        \
        float xp_ = a_[0]*a_[0]+a_[1]*a_[1]+a_[2]*a_[2]+a_[3]*a_[3]            \
                  + b_[0]*b_[0]+b_[1]*b_[1]+b_[2]*b_[2]+b_[3]*b_[3]            \
                  + c_[0]*c_[0]+c_[1]*c_[1]+c_[2]*c_[2]+c_[3]*c_[3]            \
                  + d_[0]*d_[0]+d_[1]*d_[1]+d_[2]*d_[2]+d_[3]*d_[3];           \
        xp_ += __shfl_xor(xp_, 16, 64);  xp_ += __shfl_xor(xp_, 32, 64);       \
        XN = xp_;                                                              \
        U8 q_; short8 A0_, A1_;                                                \
        CVT8(q_, a_, b_) A0_ = q_.s;                                           \
        CVT8(q_, c_, d_) A1_ = q_.s;                                           \
        KSTEP(0, B00, B01, ic0, BV0, BV1, BV2, BV3)                            \
        KSTEP(1, B10, B11, ic1, BV0, BV1, BV2, BV3)                            \
        KSTEP(2, B20, B21, ic2, BV0, BV1, BV2, BV3)                            \
        KSTEP(3, B30, B31, ic3, BV0, BV1, BV2, BV3) }

    TILE(0, bv00, bv01, bv02, bv03, xn0)
    TILE(1, bv10, bv11, bv12, bv13, xn1)
    TILE(2, bv20, bv21, bv22, bv23, xn2)
    TILE(3, bv30, bv31, bv32, bv33, xn3)
    TILE(4, bv40, bv41, bv42, bv43, xn4)
    TILE(5, bv50, bv51, bv52, bv53, xn5)
    TILE(6, bv60, bv61, bv62, bv63, xn6)
    TILE(7, bv70, bv71, bv72, bv73, xn7)
#undef TILE
#undef KSTEP

    // ---- Phase 2: fold the 16 entry-lanes (r15 dimension) of this K-slice
#define RED(BV) { BV = fmaxf(BV, __shfl_xor(BV, 1, 64));                       \
                  BV = fmaxf(BV, __shfl_xor(BV, 2, 64));                       \
                  BV = fmaxf(BV, __shfl_xor(BV, 4, 64));                       \
                  BV = fmaxf(BV, __shfl_xor(BV, 8, 64)); }
    RED(bv00) RED(bv01) RED(bv02) RED(bv03)
    RED(bv10) RED(bv11) RED(bv12) RED(bv13)
    RED(bv20) RED(bv21) RED(bv22) RED(bv23)
    RED(bv30) RED(bv31) RED(bv32) RED(bv33)
    RED(bv40) RED(bv41) RED(bv42) RED(bv43)
    RED(bv50) RED(bv51) RED(bv52) RED(bv53)
    RED(bv60) RED(bv61) RED(bv62) RED(bv63)
    RED(bv70) RED(bv71) RED(bv72) RED(bv73)
#undef RED

    // ---- Phase 3: cross-wave combine via tiny LDS
    if (r15 == 0) {                     // 4 lanes per wave (g = 0..3)
#define ST(T, BV0, BV1, BV2, BV3) {                                            \
        const int rb_ = T * 16 + (g << 2);                                     \
        lds_best[wid * 128 + rb_]     = BV0;                                   \
        lds_best[wid * 128 + rb_ + 1] = BV1;                                   \
        lds_best[wid * 128 + rb_ + 2] = BV2;                                   \
        lds_best[wid * 128 + rb_ + 3] = BV3; }
        ST(0, bv00, bv01, bv02, bv03)
        ST(1, bv10, bv11, bv12, bv13)
        ST(2, bv20, bv21, bv22, bv23)
        ST(3, bv30, bv31, bv32, bv33)
        ST(4, bv40, bv41, bv42, bv43)
        ST(5, bv50, bv51, bv52, bv53)
        ST(6, bv60, bv61, bv62, bv63)
        ST(7, bv70, bv71, bv72, bv73)
#undef ST
    }
    if (tid < 16) {                     // wave 0, g==0: row norms (all waves equal)
        lds_xn[tid]       = xn0;  lds_xn[16 + tid]  = xn1;
        lds_xn[32 + tid]  = xn2;  lds_xn[48 + tid]  = xn3;
        lds_xn[64 + tid]  = xn4;  lds_xn[80 + tid]  = xn5;
        lds_xn[96 + tid]  = xn6;  lds_xn[112 + tid] = xn7;
    }
    __syncthreads();

    float lred = 0.0f;
    if (tid < 128) {
        float m = lds_best[tid];
#pragma unroll
        for (int w = 1; w < 8; ++w) m = fmaxf(m, lds_best[w * 128 + tid]);
        const unsigned int mb = __float_as_uint(m);
        lds_idx[tid] = (int)(mb & 511u);
        lred = lds_xn[tid] - 2.0f * __uint_as_float(mb & 0xFFFFFE00u);
    }
#pragma unroll
    for (int s = 0; s < 6; ++s) lred += __shfl_xor(lred, 1 << s, 64);
    if (tid == 0)  lds_part[0] = lred;
    if (tid == 64) lds_part[1] = lred;
    __syncthreads();

    // ---- Phase 4: gather -> store (coalesced; 1 row-segment of 64B per thread)
    {
        const int erow = tid >> 2, eseg = tid & 3;
        const long eidx = (long)lds_idx[erow];
        const f4* cq = (const f4*)(cb + eidx * DIMS + eseg * 16);
        f4* op = (f4*)(out + (wgrow + erow) * DIMS + eseg * 16);
        op[0] = cq[0]; op[1] = cq[1]; op[2] = cq[2]; op[3] = cq[3];
    }
    if (tid == 0) ws[blockIdx.x] = lds_part[0] + lds_part[1];
}

__global__ __launch_bounds__(256) void vq_final(const float* __restrict__ ws,
                                                float* __restrict__ out) {
    const int t = threadIdx.x;
    float s = ws[t] + ws[t + 256] + ws[t + 512] + ws[t + 768];
#pragma unroll
    for (int st = 0; st < 6; ++st) s += __shfl_xor(s, 1 << st, 64);
    __shared__ float w2[4];
    if ((t & 63) == 0) w2[t >> 6] = s;
    __syncthreads();
    if (t == 0) {
        float total = w2[0] + w2[1] + w2[2] + w2[3];
        out[OUT_Q] = 1.25f * total / 8388608.0f;
    }
}

extern "C" void kernel_launch(void* const* d_in, const int* in_sizes, int n_in,
                              void* d_out, int out_size, void* d_ws, size_t ws_size,
                              hipStream_t stream) {
    const float* x  = (const float*)d_in[0];
    const float* cb = (const float*)d_in[1];
    float* out = (float*)d_out;
    float* ws  = (float*)d_ws;
    vq_main<<<MAIN_WGS, 512, 0, stream>>>(x, cb, out, ws);
    vq_final<<<1, 256, 0, stream>>>(ws, out);
}

// Round 9
// 40.991 us; speedup vs baseline: 1.5367x; 1.5367x over previous
//
#include <hip/hip_runtime.h>

#define DIMS 64
#define KCB 512
#define OUT_Q 8388608   // 32*64*64*64
#define MAIN_WGS 512

typedef float f32x4 __attribute__((ext_vector_type(4)));
typedef float f4    __attribute__((ext_vector_type(4)));
typedef short short8 __attribute__((ext_vector_type(8)));

// ws: float[0..512) per-WG partial loss sums. Nothing else.
// LDS per WG (66560 B):
//   byte [0..65536)     bf16 codebook packed in MFMA B-fragment order:
//                       byte = kt*2048 + h*1024 + l*16 + i*2
//                       holds cb[kt*16 + (l&15)][h*32 + ((l>>4)&3)*8 + i]
//   byte [65536..67584) float neg_half_c2[512]

static __device__ __forceinline__ unsigned int f2bf(float f) {
    unsigned int u = __float_as_uint(f);
    unsigned int r = u + 0x7FFFu + ((u >> 16) & 1u);   // RNE
    return r >> 16;
}

__global__ __launch_bounds__(512)
__attribute__((amdgpu_waves_per_eu(4, 4)))
void vq_main(const float* __restrict__ x,
             const float* __restrict__ cb,
             float* __restrict__ out,
             float* __restrict__ ws) {
    __shared__ f4 ldsv[4224];          // 67584 B: packed codebook + norms

    const int tid  = threadIdx.x;
    const int lane = tid & 63;
    const int wid  = tid >> 6;
    const int wave = blockIdx.x * 8 + wid;        // 0..4095
    const long rowbase = (long)wave * 32;         // 32 x-rows per wave (2 tiles)
    const int r15 = lane & 15;
    const int g   = lane >> 4;

    // ---- A fragments + fp32 row-norm partials FIRST (HBM loads in flight
    //      while we do the staging work below)
    short8 A00, A01, A10, A11;
    float xn0 = 0.0f, xn1 = 0.0f;
    {
        const float* xa = x + (rowbase + r15) * DIMS + g * 8;
#define LOADA(FR, OFF, XN)                                                     \
        {                                                                      \
            const f4* p_ = (const f4*)(xa + (OFF));                            \
            f4 a_ = p_[0], b_ = p_[1];                                         \
            XN += a_[0]*a_[0] + a_[1]*a_[1] + a_[2]*a_[2] + a_[3]*a_[3]        \
                + b_[0]*b_[0] + b_[1]*b_[1] + b_[2]*b_[2] + b_[3]*b_[3];       \
            union { unsigned int u[4]; short8 s; } q_;                         \
            asm("v_cvt_pk_bf16_f32 %0, %1, %2" : "=v"(q_.u[0]) : "v"(a_[0]), "v"(a_[1])); \
            asm("v_cvt_pk_bf16_f32 %0, %1, %2" : "=v"(q_.u[1]) : "v"(a_[2]), "v"(a_[3])); \
            asm("v_cvt_pk_bf16_f32 %0, %1, %2" : "=v"(q_.u[2]) : "v"(b_[0]), "v"(b_[1])); \
            asm("v_cvt_pk_bf16_f32 %0, %1, %2" : "=v"(q_.u[3]) : "v"(b_[2]), "v"(b_[3])); \
            FR = q_.s;                                                         \
        }
        LOADA(A00, 0, xn0)
        LOADA(A01, 32, xn0)
        LOADA(A10, 16 * DIMS, xn1)
        LOADA(A11, 16 * DIMS + 32, xn1)
#undef LOADA
    }
    // full row norms: fold the 4 g-groups (lane keeps ||x_row(r15,tile)||^2)
    xn0 += __shfl_xor(xn0, 16, 64);  xn0 += __shfl_xor(xn0, 32, 64);
    xn1 += __shfl_xor(xn1, 16, 64);  xn1 += __shfl_xor(xn1, 32, 64);

    // ---- stage: pack fp32 codebook (L2/L3-resident) -> bf16 B-fragment LDS
    {
#pragma unroll
        for (int i = 0; i < 8; ++i) {
            const int s = tid + i * 512;          // slice id; LDS byte = s*16
            const int kt = s >> 7, rest = s & 127;
            const int h = rest >> 6, l = rest & 63;
            const int row = kt * 16 + (l & 15);
            const int col = h * 32 + ((l >> 4) & 3) * 8;
            const f4* p = (const f4*)(cb + row * DIMS + col);
            f4 u0 = p[0], u1 = p[1];
            union { unsigned int u[4]; f4 f; } q;
            q.u[0] = (f2bf(u0[1]) << 16) | f2bf(u0[0]);
            q.u[1] = (f2bf(u0[3]) << 16) | f2bf(u0[2]);
            q.u[2] = (f2bf(u1[1]) << 16) | f2bf(u1[0]);
            q.u[3] = (f2bf(u1[3]) << 16) | f2bf(u1[2]);
            ldsv[s] = q.f;
        }
        // norms: one codebook row per thread (deterministic serial sum)
        float* ldsn_w = (float*)ldsv + 16384;
        const f4* p = (const f4*)(cb + tid * DIMS);
        float s0 = 0.0f;
#pragma unroll
        for (int i = 0; i < 16; ++i) {
            f4 v = p[i];
            s0 += v[0]*v[0] + v[1]*v[1] + v[2]*v[2] + v[3]*v[3];
        }
        ldsn_w[tid] = -0.5f * s0;
    }

    __syncthreads();   // LDS codebook + norms ready

    // ---- mantissa-packed argmax state (low 9 bits of score carry k)
    float bv00 = -3.4e38f, bv01 = -3.4e38f, bv02 = -3.4e38f, bv03 = -3.4e38f;
    float bv10 = -3.4e38f, bv11 = -3.4e38f, bv12 = -3.4e38f, bv13 = -3.4e38f;

    const char*  ldsb = (const char*)ldsv;
    const float* ldsn = (const float*)ldsv + 16384;
    const int laneoff = lane * 16;

#define PKMAX(BV, S)                                                           \
    BV = fmaxf(BV, __uint_as_float((__float_as_uint(S) & 0xFFFFFE00u) | kr));

#pragma unroll
    for (int kt = 0; kt < 32; ++kt) {
        short8 b0 = *(const short8*)(ldsb + kt * 2048 + laneoff);
        short8 b1 = *(const short8*)(ldsb + kt * 2048 + 1024 + laneoff);
        float ic = ldsn[kt * 16 + r15];          // conflict-free broadcast read
        f32x4 init = {ic, ic, ic, ic};
        f32x4 a0 = __builtin_amdgcn_mfma_f32_16x16x32_bf16(A00, b0, init, 0, 0, 0);
        a0       = __builtin_amdgcn_mfma_f32_16x16x32_bf16(A01, b1, a0,  0, 0, 0);
        f32x4 a1 = __builtin_amdgcn_mfma_f32_16x16x32_bf16(A10, b0, init, 0, 0, 0);
        a1       = __builtin_amdgcn_mfma_f32_16x16x32_bf16(A11, b1, a1,  0, 0, 0);
        const unsigned int kr = (unsigned int)(kt * 16 + r15);
        PKMAX(bv00, a0[0]) PKMAX(bv01, a0[1]) PKMAX(bv02, a0[2]) PKMAX(bv03, a0[3])
        PKMAX(bv10, a1[0]) PKMAX(bv11, a1[1]) PKMAX(bv12, a1[2]) PKMAX(bv13, a1[3])
    }
#undef PKMAX

    // ---- argmax reduce across the 16 lanes of each row-group (k dimension)
#pragma unroll
    for (int st = 0; st < 4; ++st) {
        const int m = 1 << st;
        bv00 = fmaxf(bv00, __shfl_xor(bv00, m, 64));
        bv01 = fmaxf(bv01, __shfl_xor(bv01, m, 64));
        bv02 = fmaxf(bv02, __shfl_xor(bv02, m, 64));
        bv03 = fmaxf(bv03, __shfl_xor(bv03, m, 64));
        bv10 = fmaxf(bv10, __shfl_xor(bv10, m, 64));
        bv11 = fmaxf(bv11, __shfl_xor(bv11, m, 64));
        bv12 = fmaxf(bv12, __shfl_xor(bv12, m, 64));
        bv13 = fmaxf(bv13, __shfl_xor(bv13, m, 64));
    }

    // ---- epilogue: pure gather -> store (no x re-read)
    const int orow = lane >> 2;        // 0..15: row within tile
    const int cseg = lane & 3;         // 16-float column segment
    const int j2   = orow & 3;
    int idx0 = (int)(__float_as_uint(j2 == 0 ? bv00 : j2 == 1 ? bv01 : j2 == 2 ? bv02 : bv03) & 511u);
    int idx1 = (int)(__float_as_uint(j2 == 0 ? bv10 : j2 == 1 ? bv11 : j2 == 2 ? bv12 : bv13) & 511u);

#define EPI(IDX, TOFF)                                                     \
    {                                                                      \
        const long row_ = rowbase + (TOFF) + orow;                         \
        const f4* cq_ = (const f4*)(cb + (long)(IDX) * DIMS + cseg * 16);  \
        f4* op_      = (f4*)(out + row_ * DIMS + cseg * 16);               \
        _Pragma("unroll")                                                  \
        for (int u = 0; u < 4; ++u) op_[u] = cq_[u];                       \
    }
    EPI(idx0, 0)
    EPI(idx1, 16)
#undef EPI

    // ---- loss from scores: ||q-x||^2 = ||x||^2 - 2*best  (no x re-read)
    float lsum = 0.0f;
    if (g == (r15 >> 2)) {             // this lane's bv row (g*4+j') == its r15 row
        const int jp = r15 & 3;
#define SSEL(T) __uint_as_float(__float_as_uint(jp == 0 ? bv##T##0 : jp == 1 ? bv##T##1 : \
                                jp == 2 ? bv##T##2 : bv##T##3) & 0xFFFFFE00u)
        lsum = (xn0 - 2.0f * SSEL(0)) + (xn1 - 2.0f * SSEL(1));
#undef SSEL
    }
#pragma unroll
    for (int s = 0; s < 6; ++s) lsum += __shfl_xor(lsum, 1 << s, 64);

    __syncthreads();                   // all waves done reading lds codebook
    float* lsred = (float*)ldsv;
    if (lane == 0) lsred[wid] = lsum;
    __syncthreads();
    if (tid == 0) {
        ws[blockIdx.x] = lsred[0] + lsred[1] + lsred[2] + lsred[3]
                       + lsred[4] + lsred[5] + lsred[6] + lsred[7];
    }
}

__global__ __launch_bounds__(256) void vq_final(const float* __restrict__ ws,
                                                float* __restrict__ out) {
    const int t = threadIdx.x;
    float s = ws[t] + ws[t + 256];
#pragma unroll
    for (int st = 0; st < 6; ++st) s += __shfl_xor(s, 1 << st, 64);
    __shared__ float w2[4];
    if ((t & 63) == 0) w2[t >> 6] = s;
    __syncthreads();
    if (t == 0) {
        float total = w2[0] + w2[1] + w2[2] + w2[3];
        out[OUT_Q] = 1.25f * total / 8388608.0f;
    }
}

extern "C" void kernel_launch(void* const* d_in, const int* in_sizes, int n_in,
                              void* d_out, int out_size, void* d_ws, size_t ws_size,
                              hipStream_t stream) {
    const float* x  = (const float*)d_in[0];
    const float* cb = (const float*)d_in[1];
    float* out = (float*)d_out;
    float* ws  = (float*)d_ws;
    vq_main<<<MAIN_WGS, 512, 0, stream>>>(x, cb, out, ws);
    vq_final<<<1, 256, 0, stream>>>(ws, out);
}

// Round 10
// 32.649 us; speedup vs baseline: 1.9294x; 1.2555x over previous
//
#include <hip/hip_runtime.h>

#define DIMS 64
#define KCB 512
#define OUT_Q 8388608   // 32*64*64*64
#define MAIN_WGS 512

typedef float f32x4 __attribute__((ext_vector_type(4)));
typedef float f4    __attribute__((ext_vector_type(4)));
typedef short short8 __attribute__((ext_vector_type(8)));

// ws layout:
//   float [0..512)      per-WG partial loss sums
//   float [512..1024)   neg_half_c2[512]  (= -0.5*||c_k||^2)
//   byte  [4096..69632) bf16 codebook packed in MFMA B-fragment order:
//                       byte = 4096 + kt*2048 + h*1024 + l*16 + i*2
//                       holds cb[kt*16 + (l&15)][h*32 + ((l>>4)&3)*8 + i]

static __device__ __forceinline__ unsigned int f2bf(float f) {
    unsigned int u = __float_as_uint(f);
    unsigned int r = u + 0x7FFFu + ((u >> 16) & 1u);   // RNE
    return r >> 16;
}

__global__ void vq_prep(const float* __restrict__ cb, float* __restrict__ ws) {
    int t = blockIdx.x * blockDim.x + threadIdx.x;   // 0..4607
    if (t < 4096) {
        // pack one 16-byte B-fragment slice
        int kt = t >> 7, rest = t & 127;
        int h = rest >> 6, l = rest & 63;
        int row = kt * 16 + (l & 15);
        int col = h * 32 + ((l >> 4) & 3) * 8;
        const f4* p = (const f4*)(cb + row * DIMS + col);
        f4 u0 = p[0], u1 = p[1];
        unsigned int* dst = (unsigned int*)((char*)ws + 4096 + kt * 2048 + h * 1024 + l * 16);
        dst[0] = (f2bf(u0[1]) << 16) | f2bf(u0[0]);
        dst[1] = (f2bf(u0[3]) << 16) | f2bf(u0[2]);
        dst[2] = (f2bf(u1[1]) << 16) | f2bf(u1[0]);
        dst[3] = (f2bf(u1[3]) << 16) | f2bf(u1[2]);
    } else if (t < 4096 + KCB) {
        int r = t - 4096;
        const f4* p = (const f4*)(cb + r * DIMS);
        float s = 0.0f;
#pragma unroll
        for (int i = 0; i < DIMS / 4; ++i) {
            f4 v = p[i];
            s += v[0]*v[0] + v[1]*v[1] + v[2]*v[2] + v[3]*v[3];
        }
        ws[512 + r] = -0.5f * s;
    }
}

__global__ __launch_bounds__(512, 4) void vq_main(const float* __restrict__ x,
                                                  const float* __restrict__ cb,
                                                  float* __restrict__ out,
                                                  float* __restrict__ ws) {
    __shared__ f4 ldsv[4224];          // 67584 B: packed codebook + norms

    const int tid  = threadIdx.x;
    const int lane = tid & 63;
    const int wid  = tid >> 6;
    const int wave = blockIdx.x * 8 + wid;        // 0..4095
    const long rowbase = (long)wave * 32;         // 32 x-rows per wave (2 tiles)
    const int r15 = lane & 15;
    const int g   = lane >> 4;

    // ---- Phase 1: ISSUE all global loads as one batch (A: 8 HBM f4;
    //      staging: 8 L2 f4 + 1 norm float), pinned live before any consumer.
    const float* xa = x + (rowbase + r15) * DIMS + g * 8;
    f4 a0 = *(const f4*)(xa + 0);
    f4 a1 = *(const f4*)(xa + 4);
    f4 a2 = *(const f4*)(xa + 32);
    f4 a3 = *(const f4*)(xa + 36);
    f4 a4 = *(const f4*)(xa + 16 * DIMS);
    f4 a5 = *(const f4*)(xa + 16 * DIMS + 4);
    f4 a6 = *(const f4*)(xa + 16 * DIMS + 32);
    f4 a7 = *(const f4*)(xa + 16 * DIMS + 36);
    const f4* src = (const f4*)((const char*)ws + 4096);
    f4 s0 = src[tid];
    f4 s1 = src[512 + tid];
    f4 s2 = src[1024 + tid];
    f4 s3 = src[1536 + tid];
    f4 s4 = src[2048 + tid];
    f4 s5 = src[2560 + tid];
    f4 s6 = src[3072 + tid];
    f4 s7 = src[3584 + tid];
    float nv = ws[512 + tid];
    asm volatile("" : "+v"(a0), "+v"(a1), "+v"(a2), "+v"(a3),
                      "+v"(a4), "+v"(a5), "+v"(a6), "+v"(a7),
                      "+v"(s0), "+v"(s1), "+v"(s2), "+v"(s3),
                      "+v"(s4), "+v"(s5), "+v"(s6), "+v"(s7), "+v"(nv));

    // ---- Phase 2: convert A -> bf16 fragments + fp32 row-norm partials
    short8 A00, A01, A10, A11;
    float xn0, xn1;
    {
#define CVTPAIR(FR, PA, PB)                                                    \
        {                                                                      \
            union { unsigned int u[4]; short8 s; } q_;                         \
            asm("v_cvt_pk_bf16_f32 %0, %1, %2" : "=v"(q_.u[0]) : "v"(PA[0]), "v"(PA[1])); \
            asm("v_cvt_pk_bf16_f32 %0, %1, %2" : "=v"(q_.u[1]) : "v"(PA[2]), "v"(PA[3])); \
            asm("v_cvt_pk_bf16_f32 %0, %1, %2" : "=v"(q_.u[2]) : "v"(PB[0]), "v"(PB[1])); \
            asm("v_cvt_pk_bf16_f32 %0, %1, %2" : "=v"(q_.u[3]) : "v"(PB[2]), "v"(PB[3])); \
            FR = q_.s;                                                         \
        }
        CVTPAIR(A00, a0, a1)
        CVTPAIR(A01, a2, a3)
        CVTPAIR(A10, a4, a5)
        CVTPAIR(A11, a6, a7)
#undef CVTPAIR
#define N8(PA, PB) (PA[0]*PA[0]+PA[1]*PA[1]+PA[2]*PA[2]+PA[3]*PA[3]+           \
                    PB[0]*PB[0]+PB[1]*PB[1]+PB[2]*PB[2]+PB[3]*PB[3])
        xn0 = N8(a0, a1) + N8(a2, a3);
        xn1 = N8(a4, a5) + N8(a6, a7);
#undef N8
    }
    xn0 += __shfl_xor(xn0, 16, 64);  xn0 += __shfl_xor(xn0, 32, 64);
    xn1 += __shfl_xor(xn1, 16, 64);  xn1 += __shfl_xor(xn1, 32, 64);

    // ---- Phase 3: LDS writes of the staged batch
    ldsv[tid]        = s0;
    ldsv[512 + tid]  = s1;
    ldsv[1024 + tid] = s2;
    ldsv[1536 + tid] = s3;
    ldsv[2048 + tid] = s4;
    ldsv[2560 + tid] = s5;
    ldsv[3072 + tid] = s6;
    ldsv[3584 + tid] = s7;
    ((float*)ldsv + 16384)[tid] = nv;

    __syncthreads();   // LDS codebook + norms ready

    // ---- mantissa-packed argmax state (low 9 bits of score carry k)
    float bv00 = -3.4e38f, bv01 = -3.4e38f, bv02 = -3.4e38f, bv03 = -3.4e38f;
    float bv10 = -3.4e38f, bv11 = -3.4e38f, bv12 = -3.4e38f, bv13 = -3.4e38f;

    const char*  ldsb = (const char*)ldsv;
    const float* ldsn = (const float*)ldsv + 16384;
    const int laneoff = lane * 16;

#define PKMAX(BV, S)                                                           \
    BV = fmaxf(BV, __uint_as_float((__float_as_uint(S) & 0xFFFFFE00u) | kr));

#pragma unroll
    for (int kt = 0; kt < 32; ++kt) {
        short8 b0 = *(const short8*)(ldsb + kt * 2048 + laneoff);
        short8 b1 = *(const short8*)(ldsb + kt * 2048 + 1024 + laneoff);
        float ic = ldsn[kt * 16 + r15];          // conflict-free broadcast read
        f32x4 init = {ic, ic, ic, ic};
        f32x4 q0 = __builtin_amdgcn_mfma_f32_16x16x32_bf16(A00, b0, init, 0, 0, 0);
        q0       = __builtin_amdgcn_mfma_f32_16x16x32_bf16(A01, b1, q0,  0, 0, 0);
        f32x4 q1 = __builtin_amdgcn_mfma_f32_16x16x32_bf16(A10, b0, init, 0, 0, 0);
        q1       = __builtin_amdgcn_mfma_f32_16x16x32_bf16(A11, b1, q1,  0, 0, 0);
        const unsigned int kr = (unsigned int)(kt * 16 + r15);
        PKMAX(bv00, q0[0]) PKMAX(bv01, q0[1]) PKMAX(bv02, q0[2]) PKMAX(bv03, q0[3])
        PKMAX(bv10, q1[0]) PKMAX(bv11, q1[1]) PKMAX(bv12, q1[2]) PKMAX(bv13, q1[3])
    }
#undef PKMAX

    // ---- argmax reduce across the 16 lanes of each row-group (k dimension)
#pragma unroll
    for (int st = 0; st < 4; ++st) {
        const int m = 1 << st;
        bv00 = fmaxf(bv00, __shfl_xor(bv00, m, 64));
        bv01 = fmaxf(bv01, __shfl_xor(bv01, m, 64));
        bv02 = fmaxf(bv02, __shfl_xor(bv02, m, 64));
        bv03 = fmaxf(bv03, __shfl_xor(bv03, m, 64));
        bv10 = fmaxf(bv10, __shfl_xor(bv10, m, 64));
        bv11 = fmaxf(bv11, __shfl_xor(bv11, m, 64));
        bv12 = fmaxf(bv12, __shfl_xor(bv12, m, 64));
        bv13 = fmaxf(bv13, __shfl_xor(bv13, m, 64));
    }

    // ---- epilogue: pure gather -> store (no x re-read)
    const int orow = lane >> 2;        // 0..15: row within tile
    const int cseg = lane & 3;         // 16-float column segment
    const int j2   = orow & 3;
    int idx0 = (int)(__float_as_uint(j2 == 0 ? bv00 : j2 == 1 ? bv01 : j2 == 2 ? bv02 : bv03) & 511u);
    int idx1 = (int)(__float_as_uint(j2 == 0 ? bv10 : j2 == 1 ? bv11 : j2 == 2 ? bv12 : bv13) & 511u);

#define EPI(IDX, TOFF)                                                     \
    {                                                                      \
        const long row_ = rowbase + (TOFF) + orow;                         \
        const f4* cq_ = (const f4*)(cb + (long)(IDX) * DIMS + cseg * 16);  \
        f4* op_      = (f4*)(out + row_ * DIMS + cseg * 16);               \
        _Pragma("unroll")                                                  \
        for (int u = 0; u < 4; ++u) op_[u] = cq_[u];                       \
    }
    EPI(idx0, 0)
    EPI(idx1, 16)
#undef EPI

    // ---- loss from scores: ||q-x||^2 = ||x||^2 - 2*best  (no x re-read)
    float lsum = 0.0f;
    if (g == (r15 >> 2)) {             // this lane's bv row (g*4+j') == its r15 row
        const int jp = r15 & 3;
#define SSEL(T) __uint_as_float(__float_as_uint(jp == 0 ? bv##T##0 : jp == 1 ? bv##T##1 : \
                                jp == 2 ? bv##T##2 : bv##T##3) & 0xFFFFFE00u)
        lsum = (xn0 - 2.0f * SSEL(0)) + (xn1 - 2.0f * SSEL(1));
#undef SSEL
    }
#pragma unroll
    for (int s = 0; s < 6; ++s) lsum += __shfl_xor(lsum, 1 << s, 64);

    __syncthreads();                   // all waves done reading lds codebook
    float* lsred = (float*)ldsv;
    if (lane == 0) lsred[wid] = lsum;
    __syncthreads();
    if (tid == 0) {
        ws[blockIdx.x] = lsred[0] + lsred[1] + lsred[2] + lsred[3]
                       + lsred[4] + lsred[5] + lsred[6] + lsred[7];
    }
}

__global__ __launch_bounds__(256) void vq_final(const float* __restrict__ ws,
                                                float* __restrict__ out) {
    const int t = threadIdx.x;
    float s = ws[t] + ws[t + 256];
#pragma unroll
    for (int st = 0; st < 6; ++st) s += __shfl_xor(s, 1 << st, 64);
    __shared__ float w2[4];
    if ((t & 63) == 0) w2[t >> 6] = s;
    __syncthreads();
    if (t == 0) {
        float total = w2[0] + w2[1] + w2[2] + w2[3];
        out[OUT_Q] = 1.25f * total / 8388608.0f;
    }
}

extern "C" void kernel_launch(void* const* d_in, const int* in_sizes, int n_in,
                              void* d_out, int out_size, void* d_ws, size_t ws_size,
                              hipStream_t stream) {
    const float* x  = (const float*)d_in[0];
    const float* cb = (const float*)d_in[1];
    float* out = (float*)d_out;
    float* ws  = (float*)d_ws;
    vq_prep<<<18, 256, 0, stream>>>(cb, ws);
    vq_main<<<MAIN_WGS, 512, 0, stream>>>(x, cb, out, ws);
    vq_final<<<1, 256, 0, stream>>>(ws, out);
}

// Round 11
// 31.443 us; speedup vs baseline: 2.0034x; 1.0384x over previous
//
#include <hip/hip_runtime.h>

#define DIMS 64
#define KCB 512
#define OUT_Q 8388608   // 32*64*64*64
#define MAIN_WGS 1024

typedef float f32x4 __attribute__((ext_vector_type(4)));
typedef float f4    __attribute__((ext_vector_type(4)));

// ws layout (bytes):
//   [0..4096)     float per-WG partial loss sums [1024]
//   [4096..6144)  float scaled norms: -128*||c_k||^2  (= -0.5*||256c||^2/256)
//   [8192..40960) fp8 e4m3(256*cb) packed in MFMA B-fragment order:
//                 byte = 8192 + kt*1024 + h*512 + l*8 + i
//                 holds fp8(256*cb[kt*16+(l&15)][h*32+((l>>4)&3)*8 + i])

static __device__ __forceinline__ unsigned int f2fp8(float f) {
    // fp32 -> OCP e4m3fn, RNE, subnormal-correct. Used only in prep (cold).
    unsigned int u = __float_as_uint(f);
    unsigned int sign = (u >> 24) & 0x80u;
    if ((u & 0x7FFFFFFFu) == 0) return sign;
    int exp = (int)((u >> 23) & 0xFFu) - 127;
    unsigned int m24 = (u & 0x7FFFFFu) | 0x800000u;
    if (exp >= -6) {
        unsigned int keep = m24 >> 20;
        unsigned int rem = m24 & 0xFFFFFu;
        if (rem > 0x80000u || (rem == 0x80000u && (keep & 1u))) keep++;
        if (keep >= 16u) { keep >>= 1; exp++; }
        int e = exp + 7;
        if (e >= 16) return sign | 0x7Eu;                       // clamp 448
        if (e == 15 && (keep & 7u) == 7u) return sign | 0x7Eu;  // avoid NaN
        return sign | ((unsigned)e << 3) | (keep & 7u);
    } else {
        int sh = 14 - exp;                   // >= 21
        if (sh > 31) return sign;            // underflow
        unsigned int keep = m24 >> sh;
        unsigned int rem = m24 & ((1u << sh) - 1u);
        unsigned int half = 1u << (sh - 1);
        if (rem > half || (rem == half && (keep & 1u))) keep++;
        if (keep >= 8u) return sign | 0x08u; // rounds up to min normal
        return sign | keep;
    }
}

__global__ void vq_prep(const float* __restrict__ cb, float* __restrict__ ws) {
    int t = blockIdx.x * blockDim.x + threadIdx.x;   // 0..4607
    if (t < 4096) {
        // pack one 8-byte fp8 B-fragment slice
        int kt = t >> 7, rest = t & 127;
        int h = rest >> 6, l = rest & 63;
        int row = kt * 16 + (l & 15);
        int col = h * 32 + ((l >> 4) & 3) * 8;
        const f4* p = (const f4*)(cb + row * DIMS + col);
        f4 u0 = p[0], u1 = p[1];
        unsigned int lo = f2fp8(256.0f * u0[0])
                        | (f2fp8(256.0f * u0[1]) << 8)
                        | (f2fp8(256.0f * u0[2]) << 16)
                        | (f2fp8(256.0f * u0[3]) << 24);
        unsigned int hi = f2fp8(256.0f * u1[0])
                        | (f2fp8(256.0f * u1[1]) << 8)
                        | (f2fp8(256.0f * u1[2]) << 16)
                        | (f2fp8(256.0f * u1[3]) << 24);
        unsigned int* dst = (unsigned int*)((char*)ws + 8192 + kt * 1024 + h * 512 + l * 8);
        dst[0] = lo;
        dst[1] = hi;
    } else if (t < 4096 + KCB) {
        int r = t - 4096;
        const f4* p = (const f4*)(cb + r * DIMS);
        float s = 0.0f;
#pragma unroll
        for (int i = 0; i < DIMS / 4; ++i) {
            f4 v = p[i];
            s += v[0]*v[0] + v[1]*v[1] + v[2]*v[2] + v[3]*v[3];
        }
        ((float*)((char*)ws + 4096))[r] = -128.0f * s;
    }
}

__global__ __launch_bounds__(512, 8) void vq_main(const float* __restrict__ x,
                                                  const float* __restrict__ cb,
                                                  float* __restrict__ out,
                                                  float* __restrict__ ws) {
    __shared__ char lds[34816];   // 32 KiB fp8 codebook + 2 KiB norms

    const int tid  = threadIdx.x;
    const int lane = tid & 63;
    const int wid  = tid >> 6;
    const long rowbase = ((long)blockIdx.x * 8 + wid) * 16;  // 16 rows per wave
    const int r15 = lane & 15;
    const int g   = lane >> 4;

    // ---- stage fp8 codebook (32 KiB) + norms (2 KiB) into LDS (linear, coalesced)
    {
        const f4* src = (const f4*)((const char*)ws + 8192);
        f4 s0 = src[tid];
        f4 s1 = src[512 + tid];
        f4 s2 = src[1024 + tid];
        f4 s3 = src[1536 + tid];
        float nv = ((const float*)((const char*)ws + 4096))[tid];
        f4* dst = (f4*)lds;
        dst[tid]        = s0;
        dst[512 + tid]  = s1;
        dst[1024 + tid] = s2;
        dst[1536 + tid] = s3;
        ((float*)(lds + 32768))[tid] = nv;
    }

    // ---- x row (16 rows/wave): load 16 floats/lane, fp8 A-frags + fp32 norm
    unsigned long A0, A1;
    float xn0;
    {
        const float* xa = x + (rowbase + r15) * DIMS + g * 8;
        f4 a0 = *(const f4*)(xa);
        f4 a1 = *(const f4*)(xa + 4);
        f4 a2 = *(const f4*)(xa + 32);
        f4 a3 = *(const f4*)(xa + 36);
        xn0 = a0[0]*a0[0]+a0[1]*a0[1]+a0[2]*a0[2]+a0[3]*a0[3]
            + a1[0]*a1[0]+a1[1]*a1[1]+a1[2]*a1[2]+a1[3]*a1[3]
            + a2[0]*a2[0]+a2[1]*a2[1]+a2[2]*a2[2]+a2[3]*a2[3]
            + a3[0]*a3[0]+a3[1]*a3[1]+a3[2]*a3[2]+a3[3]*a3[3];
        unsigned int t0, t1, t2, t3, t4, t5, t6, t7;
        asm("v_cvt_pk_fp8_f32 %0, %1, %2" : "=v"(t0) : "v"(a0[0]), "v"(a0[1]));
        asm("v_cvt_pk_fp8_f32 %0, %1, %2" : "=v"(t1) : "v"(a0[2]), "v"(a0[3]));
        asm("v_cvt_pk_fp8_f32 %0, %1, %2" : "=v"(t2) : "v"(a1[0]), "v"(a1[1]));
        asm("v_cvt_pk_fp8_f32 %0, %1, %2" : "=v"(t3) : "v"(a1[2]), "v"(a1[3]));
        asm("v_cvt_pk_fp8_f32 %0, %1, %2" : "=v"(t4) : "v"(a2[0]), "v"(a2[1]));
        asm("v_cvt_pk_fp8_f32 %0, %1, %2" : "=v"(t5) : "v"(a2[2]), "v"(a2[3]));
        asm("v_cvt_pk_fp8_f32 %0, %1, %2" : "=v"(t6) : "v"(a3[0]), "v"(a3[1]));
        asm("v_cvt_pk_fp8_f32 %0, %1, %2" : "=v"(t7) : "v"(a3[2]), "v"(a3[3]));
        unsigned int dw0 = (t0 & 0xFFFFu) | (t1 << 16);
        unsigned int dw1 = (t2 & 0xFFFFu) | (t3 << 16);
        unsigned int dw2 = (t4 & 0xFFFFu) | (t5 << 16);
        unsigned int dw3 = (t6 & 0xFFFFu) | (t7 << 16);
        A0 = (unsigned long)dw0 | ((unsigned long)dw1 << 32);
        A1 = (unsigned long)dw2 | ((unsigned long)dw3 << 32);
    }
    // full row norm: fold the 4 g-groups (lane keeps ||x_row(r15)||^2)
    xn0 += __shfl_xor(xn0, 16, 64);
    xn0 += __shfl_xor(xn0, 32, 64);

    __syncthreads();   // LDS codebook + norms ready

    // ---- mantissa-packed argmax state (low 9 bits of score carry k)
    float bv0 = -3.4e38f, bv1 = -3.4e38f, bv2 = -3.4e38f, bv3 = -3.4e38f;

    const char*  ldsb = lds;
    const float* ldsn = (const float*)(lds + 32768);
    const int laneoff = lane * 8;

#pragma unroll
    for (int kt = 0; kt < 32; ++kt) {
        unsigned long b0 = *(const unsigned long*)(ldsb + kt * 1024 + laneoff);
        unsigned long b1 = *(const unsigned long*)(ldsb + kt * 1024 + 512 + laneoff);
        float ic = ldsn[kt * 16 + r15];          // conflict-free broadcast read
        f32x4 init = {ic, ic, ic, ic};
        f32x4 q = __builtin_amdgcn_mfma_f32_16x16x32_fp8_fp8((long)A0, (long)b0, init, 0, 0, 0);
        q       = __builtin_amdgcn_mfma_f32_16x16x32_fp8_fp8((long)A1, (long)b1, q,    0, 0, 0);
        const unsigned int kr = (unsigned int)(kt * 16 + r15);
        bv0 = fmaxf(bv0, __uint_as_float((__float_as_uint(q[0]) & 0xFFFFFE00u) | kr));
        bv1 = fmaxf(bv1, __uint_as_float((__float_as_uint(q[1]) & 0xFFFFFE00u) | kr));
        bv2 = fmaxf(bv2, __uint_as_float((__float_as_uint(q[2]) & 0xFFFFFE00u) | kr));
        bv3 = fmaxf(bv3, __uint_as_float((__float_as_uint(q[3]) & 0xFFFFFE00u) | kr));
    }

    // ---- argmax reduce across the 16 entry-lanes of each row-group
#pragma unroll
    for (int st = 0; st < 4; ++st) {
        const int m = 1 << st;
        bv0 = fmaxf(bv0, __shfl_xor(bv0, m, 64));
        bv1 = fmaxf(bv1, __shfl_xor(bv1, m, 64));
        bv2 = fmaxf(bv2, __shfl_xor(bv2, m, 64));
        bv3 = fmaxf(bv3, __shfl_xor(bv3, m, 64));
    }

    // ---- epilogue: pure gather -> store (no x re-read)
    {
        const int orow = lane >> 2;        // 0..15; orow>>2 == g always
        const int cseg = lane & 3;
        const int j2   = orow & 3;
        const int idx = (int)(__float_as_uint(j2 == 0 ? bv0 : j2 == 1 ? bv1 :
                                              j2 == 2 ? bv2 : bv3) & 511u);
        const f4* cq = (const f4*)(cb + (long)idx * DIMS + cseg * 16);
        f4* op = (f4*)(out + (rowbase + orow) * DIMS + cseg * 16);
        op[0] = cq[0]; op[1] = cq[1]; op[2] = cq[2]; op[3] = cq[3];
    }

    // ---- loss from scores: ||q-x||^2 = ||x||^2 - 2*(s'/256) = xn - s'/128
    float lsum = 0.0f;
    if (g == (r15 >> 2)) {                 // one lane per row r15
        const int jp = r15 & 3;
        float s0 = jp == 0 ? bv0 : jp == 1 ? bv1 : jp == 2 ? bv2 : bv3;
        s0 = __uint_as_float(__float_as_uint(s0) & 0xFFFFFE00u);
        lsum = xn0 - s0 * 0.0078125f;
    }
#pragma unroll
    for (int s = 0; s < 6; ++s) lsum += __shfl_xor(lsum, 1 << s, 64);

    __syncthreads();                       // all waves done reading lds codebook
    float* lsred = (float*)lds;
    if (lane == 0) lsred[wid] = lsum;
    __syncthreads();
    if (tid == 0) {
        ws[blockIdx.x] = lsred[0] + lsred[1] + lsred[2] + lsred[3]
                       + lsred[4] + lsred[5] + lsred[6] + lsred[7];
    }
}

__global__ __launch_bounds__(256) void vq_final(const float* __restrict__ ws,
                                                float* __restrict__ out) {
    const int t = threadIdx.x;
    float s = ws[t] + ws[t + 256] + ws[t + 512] + ws[t + 768];
#pragma unroll
    for (int st = 0; st < 6; ++st) s += __shfl_xor(s, 1 << st, 64);
    __shared__ float w2[4];
    if ((t & 63) == 0) w2[t >> 6] = s;
    __syncthreads();
    if (t == 0) {
        float total = w2[0] + w2[1] + w2[2] + w2[3];
        out[OUT_Q] = 1.25f * total / 8388608.0f;
    }
}

extern "C" void kernel_launch(void* const* d_in, const int* in_sizes, int n_in,
                              void* d_out, int out_size, void* d_ws, size_t ws_size,
                              hipStream_t stream) {
    const float* x  = (const float*)d_in[0];
    const float* cb = (const float*)d_in[1];
    float* out = (float*)d_out;
    float* ws  = (float*)d_ws;
    vq_prep<<<18, 256, 0, stream>>>(cb, ws);
    vq_main<<<MAIN_WGS, 512, 0, stream>>>(x, cb, out, ws);
    vq_final<<<1, 256, 0, stream>>>(ws, out);
}